// Round 14
// baseline (831.160 us; speedup 1.0000x reference)
//
#include <hip/hip_runtime.h>
#include <math.h>

#define LSEQ   1080
#define NBATCH 16
#define BLROWS (LSEQ*NBATCH)   // 17280
#define CHN    27
#define LCH    40              // 27*40 = 1080

#define LPAD 44
#define LPADB 140

typedef __bf16  bf16x8 __attribute__((ext_vector_type(8)));
typedef float   f32x4  __attribute__((ext_vector_type(4)));
typedef short   short8 __attribute__((ext_vector_type(8)));
typedef short   short4v __attribute__((ext_vector_type(4)));

__device__ __forceinline__ float silu_f(float x) { return x / (1.f + __expf(-x)); }

__device__ __forceinline__ unsigned short f2bf(float f) {
    unsigned int u = __float_as_uint(f);
    u += 0x7fffu + ((u >> 16) & 1u);
    return (unsigned short)(u >> 16);
}
__device__ __forceinline__ float bf2f(unsigned short h) {
    return __uint_as_float(((unsigned int)h) << 16);
}
__device__ __forceinline__ void split_bf(float v, unsigned short& h, unsigned short& l) {
    h = f2bf(v);
    l = f2bf(v - bf2f(h));
}

// ---------------- embed + positional encoding (fp32 + pre-split hi/lo) ------
__global__ __launch_bounds__(256) void embed_kernel(
    const float* __restrict__ x, const float* __restrict__ embW,
    const float* __restrict__ embb, float* __restrict__ xe,
    unsigned short* __restrict__ xeh, unsigned short* __restrict__ xel)
{
    int idx = blockIdx.x * 256 + threadIdx.x;
    if (idx >= BLROWS * 128) return;
    int d = idx & 127;
    int r = idx >> 7;
    int t = r % LSEQ;
    float x0 = x[(size_t)r * 2], x1 = x[(size_t)r * 2 + 1];
    int i2 = d & 126;
    float div = expf((float)i2 * (-9.210340371976184f / 128.f));
    float arg = (float)t * div;
    float pe = (d & 1) ? cosf(arg) : sinf(arg);
    float v = fmaf(x0, embW[d], fmaf(x1, embW[128 + d], embb[d] + pe));
    xe[idx] = v;
    unsigned short h, l;
    split_bf(v, h, l);
    xeh[idx] = h; xel[idx] = l;
}

// ---------------- all weight conversions + scale/shift packing --------------
#define JOB_W192  172032
#define JOB_CF    196608
#define JOB_IN    393216
#define JOB_XP    442368
#define JOB_OT    540672
#define JOB_FL    573440
#define JOB_END   574080
__global__ __launch_bounds__(256) void convw_all(
    const float* __restrict__ c3W, const float* __restrict__ c5W,
    const float* __restrict__ c7W, const float* __restrict__ cfW,
    const float* __restrict__ inW, const float* __restrict__ xpW,
    const float* __restrict__ otW, const float* __restrict__ flW,
    const float* __restrict__ c3b, const float* __restrict__ c5b, const float* __restrict__ c7b,
    const float* __restrict__ bn3, const float* __restrict__ bn5, const float* __restrict__ bn7,
    const float* __restrict__ cfb, const float* __restrict__ bnf,
    unsigned short* __restrict__ w192h, unsigned short* __restrict__ w192l,
    unsigned short* __restrict__ cfh, unsigned short* __restrict__ cfl,
    unsigned short* __restrict__ inh, unsigned short* __restrict__ inl,
    unsigned short* __restrict__ xph, unsigned short* __restrict__ xpl,
    unsigned short* __restrict__ oth, unsigned short* __restrict__ otl,
    unsigned short* __restrict__ flh, unsigned short* __restrict__ fll,
    float* __restrict__ schpack)
{
    int idx = blockIdx.x * 256 + threadIdx.x;
    if (idx >= JOB_END) return;
    float v;
    unsigned short *dh, *dl;
    int off;
    if (idx < JOB_W192) {
        off = idx;
        int n = off / 896, kk = off % 896;
        int slot = kk >> 7, d = kk & 127;
        int br = n >> 6, c = n & 63;
        int KT = 3 + 2 * br, pad = 1 + br;
        int tp = slot - 3 + pad;
        const float* w = (br == 0) ? c3W : (br == 1) ? c5W : c7W;
        v = (tp >= 0 && tp < KT) ? w[((c << 7) + d) * KT + tp] : 0.f;
        dh = w192h; dl = w192l;
    } else if (idx < JOB_CF) {
        off = idx - JOB_W192; v = cfW[off]; dh = cfh; dl = cfl;
    } else if (idx < JOB_IN) {
        off = idx - JOB_CF; v = inW[off]; dh = inh; dl = inl;
    } else if (idx < JOB_XP) {
        off = idx - JOB_IN;
        int k = off & 255, n = (off >> 8) & 63, blk = off >> 14;
        v = (n < 40) ? xpW[((size_t)blk * 40 + n) * 256 + k] : 0.f;
        dh = xph; dl = xpl;
    } else if (idx < JOB_OT) {
        off = idx - JOB_XP; v = otW[off]; dh = oth; dl = otl;
    } else if (idx < JOB_FL) {
        off = idx - JOB_OT; v = flW[off]; dh = flh; dl = fll;
    } else {
        int j = idx - JOB_FL;
        if (j < 384) {
            int col = (j < 192) ? j : j - 192;
            int isSh = j >= 192;
            int br = col >> 6, c = col & 63;
            const float* bn = (br == 0) ? bn3 : (br == 1) ? bn5 : bn7;
            float bias = ((br == 0) ? c3b : (br == 1) ? c5b : c7b)[c];
            float g = bn[c], bb = bn[64 + c], m = bn[128 + c], vv = bn[192 + c];
            float scale = g * rsqrtf(vv + 1e-5f);
            float shift = (bias - m) * scale + bb;
            schpack[j] = isSh ? shift : scale;
        } else {
            int j2 = j - 384;
            int col = j2 & 127;
            int isSh = j2 >= 128;
            float g = bnf[col], bb = bnf[128 + col], m = bnf[256 + col], vv = bnf[384 + col];
            float scale = g * rsqrtf(vv + 1e-5f);
            float shift = (cfb[col] - m) * scale + bb;
            schpack[384 + j2] = isSh ? shift : scale;
        }
        return;
    }
    unsigned short h, l;
    split_bf(v, h, l);
    dh[off] = h; dl[off] = l;
}

// ---------------- CNN front-end: halo GEMM over unified 7-tap weights -------
__global__ __launch_bounds__(256) void gemm_conv(
    const unsigned short* __restrict__ Xh, const unsigned short* __restrict__ Xl,
    const unsigned short* __restrict__ Wh, const unsigned short* __restrict__ Wl,
    const float* __restrict__ sc, const float* __restrict__ sh,
    unsigned short* __restrict__ Ch, unsigned short* __restrict__ Cl)
{
    __shared__ unsigned short Ah[70][LPAD], Al[70][LPAD];
    __shared__ unsigned short Bh[64][LPADB], Bl[64][LPADB];
    const int tid = threadIdx.x;
    const int n0 = blockIdx.x * 64, t0 = blockIdx.y * 64, b = blockIdx.z;
    const size_t boff = (size_t)b * LSEQ;
    const int lane = tid & 63, wid = tid >> 6;
    const int wr = wid >> 1, wc = wid & 1;
    const int fr = lane & 15, fq = lane >> 4;
    const short8 zz = {0, 0, 0, 0, 0, 0, 0, 0};
    f32x4 acc[2][2];
#pragma unroll
    for (int m = 0; m < 2; ++m)
#pragma unroll
        for (int n = 0; n < 2; ++n) acc[m][n] = (f32x4){0.f, 0.f, 0.f, 0.f};

    for (int ks = 0; ks < 128; ks += 32) {
#pragma unroll
        for (int l = 0; l < 2; ++l) {
            int c = tid + l * 256;
            if (c < 280) {
                int row = c >> 2, kc = (c & 3) << 3;
                int ts = t0 - 3 + row;
                short8 vh = zz, vl = zz;
                if (ts >= 0 && ts < LSEQ) {
                    size_t s = (boff + ts) * 128 + ks + kc;
                    vh = *(const short8*)&Xh[s];
                    vl = *(const short8*)&Xl[s];
                }
                *(short8*)&Ah[row][kc] = vh;
                *(short8*)&Al[row][kc] = vl;
            }
        }
        for (int g = 0; g < 2; ++g) {
            const int ntap = (g == 0) ? 4 : 3;
#pragma unroll
            for (int l = 0; l < 4; ++l) {
                int c = tid + l * 256;
                int col = c >> 4, rem = c & 15, tt = rem >> 2, kq = (rem & 3) << 3;
                if (tt < ntap) {
                    int tap = g * 4 + tt;
                    size_t s = (size_t)(n0 + col) * 896 + tap * 128 + ks + kq;
                    *(short8*)&Bh[col][tt * 32 + kq] = *(const short8*)&Wh[s];
                    *(short8*)&Bl[col][tt * 32 + kq] = *(const short8*)&Wl[s];
                }
            }
            __syncthreads();
            for (int tt = 0; tt < ntap; ++tt) {
                int tap = g * 4 + tt;
                bf16x8 bhf[2], blf[2];
#pragma unroll
                for (int n = 0; n < 2; ++n) {
                    int col = wc * 32 + n * 16 + fr;
                    bhf[n] = __builtin_bit_cast(bf16x8, *(const short8*)&Bh[col][tt * 32 + fq * 8]);
                    blf[n] = __builtin_bit_cast(bf16x8, *(const short8*)&Bl[col][tt * 32 + fq * 8]);
                }
#pragma unroll
                for (int m = 0; m < 2; ++m) {
                    int rowA = wr * 32 + m * 16 + fr + tap;
                    bf16x8 ahf = __builtin_bit_cast(bf16x8, *(const short8*)&Ah[rowA][fq * 8]);
                    bf16x8 alf = __builtin_bit_cast(bf16x8, *(const short8*)&Al[rowA][fq * 8]);
#pragma unroll
                    for (int n = 0; n < 2; ++n) {
                        acc[m][n] = __builtin_amdgcn_mfma_f32_16x16x32_bf16(ahf, bhf[n], acc[m][n], 0, 0, 0);
                        acc[m][n] = __builtin_amdgcn_mfma_f32_16x16x32_bf16(ahf, blf[n], acc[m][n], 0, 0, 0);
                        acc[m][n] = __builtin_amdgcn_mfma_f32_16x16x32_bf16(alf, bhf[n], acc[m][n], 0, 0, 0);
                    }
                }
            }
            __syncthreads();
        }
    }
    unsigned short* Chb = Ch + (size_t)b * LSEQ * 192;
    unsigned short* Clb = Cl + (size_t)b * LSEQ * 192;
#pragma unroll
    for (int m = 0; m < 2; ++m) {
#pragma unroll
        for (int n = 0; n < 2; ++n) {
            int colg = n0 + wc * 32 + n * 16 + fr;
            float scl = sc[colg], shf2 = sh[colg];
#pragma unroll
            for (int r = 0; r < 4; ++r) {
                int t = t0 + wr * 32 + m * 16 + fq * 4 + r;
                if (t >= LSEQ) continue;
                float v = fmaf(acc[m][n][r], scl, shf2);
                v = v > 0.f ? v : 0.f;
                unsigned short h, l;
                split_bf(v, h, l);
                Chb[(size_t)t * 192 + colg] = h;
                Clb[(size_t)t * 192 + colg] = l;
            }
        }
    }
}

// ---------------- generic MFMA GEMM, pre-split A and W ----------------------
// epi: 0 fp32 | 1 relu(sc,sh)->hi/lo | 2 relu+bias fp32 | 3 hi/lo
//      4 layernorm(sc=gamma,sh=beta)->hi/lo (BM=64,BN=128,grid.x=1 only)
template<int BM, int BN>
__global__ __launch_bounds__(256) void gemm_plain(
    const unsigned short* __restrict__ Aph, const unsigned short* __restrict__ Apl, int lda,
    const unsigned short* __restrict__ Wh, const unsigned short* __restrict__ Wl, int Kd,
    int Ntot, int epi,
    const float* __restrict__ sc, const float* __restrict__ sh, const float* __restrict__ bias,
    float* __restrict__ Cf, int ldc,
    unsigned short* __restrict__ Ch, unsigned short* __restrict__ Cl, int ldch)
{
    constexpr int WM = BM / 2, WN = BN / 2;
    constexpr int MR = WM / 16, NR = WN / 16;
    constexpr int ACH = (BM * 4) / 256;
    constexpr int BCH = (BN * 4) / 256;
    __shared__ unsigned short Ah[BM][LPAD], Al[BM][LPAD];
    __shared__ unsigned short Bh[BN][LPAD], Bl[BN][LPAD];
    const int tid = threadIdx.x;
    const int b = blockIdx.z, t0 = blockIdx.y * BM, n0 = blockIdx.x * BN;
    const unsigned short* Abh = Aph + (size_t)b * LSEQ * lda;
    const unsigned short* Abl = Apl + (size_t)b * LSEQ * lda;
    const int lane = tid & 63, wid = tid >> 6;
    const int wr = wid >> 1, wc = wid & 1;
    const int fr = lane & 15, fq = lane >> 4;
    f32x4 acc[MR][NR];
#pragma unroll
    for (int m = 0; m < MR; ++m)
#pragma unroll
        for (int n = 0; n < NR; ++n) acc[m][n] = (f32x4){0.f, 0.f, 0.f, 0.f};

    const short8 zz = {0, 0, 0, 0, 0, 0, 0, 0};
    for (int ks = 0; ks < Kd; ks += 32) {
#pragma unroll
        for (int l = 0; l < ACH; ++l) {
            int c = tid + l * 256;
            int row = c >> 2, kc = (c & 3) << 3;
            int t = t0 + row;
            short8 vh = zz, vl = zz;
            if (t < LSEQ) {
                size_t s = (size_t)t * lda + ks + kc;
                vh = *(const short8*)&Abh[s];
                vl = *(const short8*)&Abl[s];
            }
            *(short8*)&Ah[row][kc] = vh;
            *(short8*)&Al[row][kc] = vl;
        }
#pragma unroll
        for (int l = 0; l < BCH; ++l) {
            int c = tid + l * 256;
            int col = c >> 2, kc = (c & 3) << 3;
            size_t s = (size_t)(n0 + col) * Kd + ks + kc;
            *(short8*)&Bh[col][kc] = *(const short8*)&Wh[s];
            *(short8*)&Bl[col][kc] = *(const short8*)&Wl[s];
        }
        __syncthreads();
        bf16x8 bhf[NR], blf[NR];
#pragma unroll
        for (int n = 0; n < NR; ++n) {
            int col = wc * WN + n * 16 + fr;
            bhf[n] = __builtin_bit_cast(bf16x8, *(const short8*)&Bh[col][fq * 8]);
            blf[n] = __builtin_bit_cast(bf16x8, *(const short8*)&Bl[col][fq * 8]);
        }
#pragma unroll
        for (int m = 0; m < MR; ++m) {
            int rowr = wr * WM + m * 16 + fr;
            bf16x8 ahf = __builtin_bit_cast(bf16x8, *(const short8*)&Ah[rowr][fq * 8]);
            bf16x8 alf = __builtin_bit_cast(bf16x8, *(const short8*)&Al[rowr][fq * 8]);
#pragma unroll
            for (int n = 0; n < NR; ++n) {
                acc[m][n] = __builtin_amdgcn_mfma_f32_16x16x32_bf16(ahf, bhf[n], acc[m][n], 0, 0, 0);
                acc[m][n] = __builtin_amdgcn_mfma_f32_16x16x32_bf16(ahf, blf[n], acc[m][n], 0, 0, 0);
                acc[m][n] = __builtin_amdgcn_mfma_f32_16x16x32_bf16(alf, bhf[n], acc[m][n], 0, 0, 0);
            }
        }
        __syncthreads();
    }

    float* Cfb = Cf ? Cf + (size_t)b * LSEQ * ldc : nullptr;
    unsigned short* Chb = Ch ? Ch + (size_t)b * LSEQ * ldch : nullptr;
    unsigned short* Clb = Cl ? Cl + (size_t)b * LSEQ * ldch : nullptr;

    if (epi == 4) {
        float* red = reinterpret_cast<float*>(&Ah[0][0]);   // [64][2]
        float part[MR][4], mu[MR][4], rs[MR][4];
#pragma unroll
        for (int m = 0; m < MR; ++m)
#pragma unroll
            for (int r = 0; r < 4; ++r) {
                float p = 0.f;
#pragma unroll
                for (int n = 0; n < NR; ++n) p += acc[m][n][r];
#pragma unroll
                for (int o2 = 1; o2 < 16; o2 <<= 1) p += __shfl_xor(p, o2, 64);
                part[m][r] = p;
            }
        if (fr == 0) {
#pragma unroll
            for (int m = 0; m < MR; ++m)
#pragma unroll
                for (int r = 0; r < 4; ++r)
                    red[(wr * 32 + m * 16 + fq * 4 + r) * 2 + wc] = part[m][r];
        }
        __syncthreads();
#pragma unroll
        for (int m = 0; m < MR; ++m)
#pragma unroll
            for (int r = 0; r < 4; ++r) {
                int row = wr * 32 + m * 16 + fq * 4 + r;
                mu[m][r] = (red[row * 2] + red[row * 2 + 1]) * (1.f / 128.f);
            }
        __syncthreads();
#pragma unroll
        for (int m = 0; m < MR; ++m)
#pragma unroll
            for (int r = 0; r < 4; ++r) {
                float p = 0.f;
#pragma unroll
                for (int n = 0; n < NR; ++n) {
                    float dv = acc[m][n][r] - mu[m][r];
                    p = fmaf(dv, dv, p);
                }
#pragma unroll
                for (int o2 = 1; o2 < 16; o2 <<= 1) p += __shfl_xor(p, o2, 64);
                part[m][r] = p;
            }
        if (fr == 0) {
#pragma unroll
            for (int m = 0; m < MR; ++m)
#pragma unroll
                for (int r = 0; r < 4; ++r)
                    red[(wr * 32 + m * 16 + fq * 4 + r) * 2 + wc] = part[m][r];
        }
        __syncthreads();
#pragma unroll
        for (int m = 0; m < MR; ++m)
#pragma unroll
            for (int r = 0; r < 4; ++r) {
                int row = wr * 32 + m * 16 + fq * 4 + r;
                rs[m][r] = rsqrtf((red[row * 2] + red[row * 2 + 1]) * (1.f / 128.f) + 1e-5f);
            }
#pragma unroll
        for (int m = 0; m < MR; ++m) {
#pragma unroll
            for (int n = 0; n < NR; ++n) {
                int colg = wc * WN + n * 16 + fr;
                float g = sc[colg], b2 = sh[colg];
#pragma unroll
                for (int r = 0; r < 4; ++r) {
                    int t = t0 + wr * WM + m * 16 + fq * 4 + r;
                    if (t >= LSEQ) continue;
                    float v = (acc[m][n][r] - mu[m][r]) * rs[m][r] * g + b2;
                    unsigned short h, l;
                    split_bf(v, h, l);
                    Chb[(size_t)t * ldch + colg] = h;
                    Clb[(size_t)t * ldch + colg] = l;
                }
            }
        }
        return;
    }

#pragma unroll
    for (int m = 0; m < MR; ++m) {
#pragma unroll
        for (int n = 0; n < NR; ++n) {
            int colg = n0 + wc * WN + n * 16 + fr;
            if (colg >= Ntot) continue;
#pragma unroll
            for (int r = 0; r < 4; ++r) {
                int t = t0 + wr * WM + m * 16 + fq * 4 + r;
                if (t >= LSEQ) continue;
                float v = acc[m][n][r];
                if (epi == 0) {
                    Cfb[(size_t)t * ldc + colg] = v;
                } else if (epi == 1) {
                    v = fmaf(v, sc[colg], sh[colg]);
                    v = v > 0.f ? v : 0.f;
                    unsigned short h, l;
                    split_bf(v, h, l);
                    Chb[(size_t)t * ldch + colg] = h;
                    Clb[(size_t)t * ldch + colg] = l;
                } else if (epi == 2) {
                    v += bias[colg];
                    v = v > 0.f ? v : 0.f;
                    Cfb[(size_t)t * ldc + colg] = v;
                } else {
                    unsigned short h, l;
                    split_bf(v, h, l);
                    Chb[(size_t)t * ldch + colg] = h;
                    Clb[(size_t)t * ldch + colg] = l;
                }
            }
        }
    }
}

// ---------------- layernorm (standalone, block 0 input only) ----------------
__global__ __launch_bounds__(256) void ln_kernel(
    const float* __restrict__ in, const float* __restrict__ g,
    const float* __restrict__ b2, unsigned short* __restrict__ oh,
    unsigned short* __restrict__ ol)
{
    int lane = threadIdx.x & 63;
    int wid  = threadIdx.x >> 6;
    int row = blockIdx.x * 4 + wid;
    if (row >= BLROWS) return;
    const float* rp = in + (size_t)row * 128;
    float v0 = rp[lane], v1 = rp[lane + 64];
    float s = v0 + v1;
#pragma unroll
    for (int o2 = 32; o2 > 0; o2 >>= 1) s += __shfl_xor(s, o2, 64);
    float mu = s * (1.f / 128.f);
    float d0 = v0 - mu, d1 = v1 - mu;
    float q = d0 * d0 + d1 * d1;
#pragma unroll
    for (int o2 = 32; o2 > 0; o2 >>= 1) q += __shfl_xor(q, o2, 64);
    float rs = 1.f / sqrtf(q * (1.f / 128.f) + 1e-5f);
    float y0 = d0 * rs * g[lane]      + b2[lane];
    float y1 = d1 * rs * g[lane + 64] + b2[lane + 64];
    unsigned short h, l;
    size_t o = (size_t)row * 128;
    split_bf(y0, h, l); oh[o + lane] = h;      ol[o + lane] = l;
    split_bf(y1, h, l); oh[o + lane + 64] = h; ol[o + lane + 64] = l;
}

// ---------------- fused mconv + x-proj GEMM + dt-softplus -------------------
// block = (t-tile 0..16, b); 256 threads; BM=64 rows, BN=64 (40 valid cols)
__global__ __launch_bounds__(256) void mxd_kernel(
    const float* __restrict__ xz, const float* __restrict__ Wc,
    const float* __restrict__ bc,
    const unsigned short* __restrict__ Wh, const unsigned short* __restrict__ Wl,
    const float* __restrict__ dtW, const float* __restrict__ dtb,
    float* __restrict__ u, float* __restrict__ dbl, float* __restrict__ dtt)
{
    __shared__ unsigned short Ah[64][72], Al[64][72];
    __shared__ unsigned short Bh[64][72], Bl[64][72];
    __shared__ float sdbl[64][44];
    const int tid = threadIdx.x;
    const int t0 = blockIdx.x * 64, b = blockIdx.y;
    const size_t rb = (size_t)b * LSEQ;
    const int lane = tid & 63, wid = tid >> 6;
    const int wr = wid >> 1, wc2 = wid & 1;
    const int fr = lane & 15, fq = lane >> 4;
    f32x4 acc[2][2];
#pragma unroll
    for (int m = 0; m < 2; ++m)
#pragma unroll
        for (int n = 0; n < 2; ++n) acc[m][n] = (f32x4){0.f, 0.f, 0.f, 0.f};

    for (int ks = 0; ks < 256; ks += 64) {
        // phase A: depthwise conv + silu for rows t0..t0+63, cols ks..ks+63
#pragma unroll
        for (int l = 0; l < 16; ++l) {
            int j = tid + l * 256;
            int row = j >> 6, cl = j & 63;
            int c = ks + cl;
            int t = t0 + row;
            unsigned short h = 0, lo = 0;
            if (t < LSEQ) {
                const float* xs = xz + (rb + t) * 512 + c;
                float a = bc[c];
                if (t >= 3) a = fmaf(xs[-3 * 512], Wc[c * 4 + 0], a);
                if (t >= 2) a = fmaf(xs[-2 * 512], Wc[c * 4 + 1], a);
                if (t >= 1) a = fmaf(xs[-1 * 512], Wc[c * 4 + 2], a);
                a = fmaf(xs[0], Wc[c * 4 + 3], a);
                float uv = silu_f(a);
                u[(rb + t) * 256 + c] = uv;
                split_bf(uv, h, lo);
            }
            Ah[row][cl] = h;
            Al[row][cl] = lo;
        }
        // phase B: xp weight tile [64 cols][64 k]
#pragma unroll
        for (int l = 0; l < 2; ++l) {
            int j = tid + l * 256;
            int col = j >> 3, kc = (j & 7) << 3;
            size_t s = (size_t)col * 256 + ks + kc;
            *(short8*)&Bh[col][kc] = *(const short8*)&Wh[s];
            *(short8*)&Bl[col][kc] = *(const short8*)&Wl[s];
        }
        __syncthreads();
#pragma unroll
        for (int kk = 0; kk < 64; kk += 32) {
            bf16x8 bhf[2], blf[2];
#pragma unroll
            for (int n = 0; n < 2; ++n) {
                int col = wc2 * 32 + n * 16 + fr;
                bhf[n] = __builtin_bit_cast(bf16x8, *(const short8*)&Bh[col][kk + fq * 8]);
                blf[n] = __builtin_bit_cast(bf16x8, *(const short8*)&Bl[col][kk + fq * 8]);
            }
#pragma unroll
            for (int m = 0; m < 2; ++m) {
                int rowr = wr * 32 + m * 16 + fr;
                bf16x8 ahf = __builtin_bit_cast(bf16x8, *(const short8*)&Ah[rowr][kk + fq * 8]);
                bf16x8 alf = __builtin_bit_cast(bf16x8, *(const short8*)&Al[rowr][kk + fq * 8]);
#pragma unroll
                for (int n = 0; n < 2; ++n) {
                    acc[m][n] = __builtin_amdgcn_mfma_f32_16x16x32_bf16(ahf, bhf[n], acc[m][n], 0, 0, 0);
                    acc[m][n] = __builtin_amdgcn_mfma_f32_16x16x32_bf16(ahf, blf[n], acc[m][n], 0, 0, 0);
                    acc[m][n] = __builtin_amdgcn_mfma_f32_16x16x32_bf16(alf, bhf[n], acc[m][n], 0, 0, 0);
                }
            }
        }
        __syncthreads();
    }

    // epilogue: dbl -> global + LDS
#pragma unroll
    for (int m = 0; m < 2; ++m) {
#pragma unroll
        for (int n = 0; n < 2; ++n) {
            int colg = wc2 * 32 + n * 16 + fr;
#pragma unroll
            for (int r = 0; r < 4; ++r) {
                int rowl = wr * 32 + m * 16 + fq * 4 + r;
                int t = t0 + rowl;
                if (colg < 40) {
                    sdbl[rowl][colg] = acc[m][n][r];
                    if (t < LSEQ)
                        dbl[(rb + t) * 40 + colg] = acc[m][n][r];
                }
            }
        }
    }
    __syncthreads();
    // dt phase: thread c = tid handles column c for all 64 rows
    {
        int c = tid;
        float w0 = dtW[c * 8 + 0], w1 = dtW[c * 8 + 1], w2 = dtW[c * 8 + 2], w3 = dtW[c * 8 + 3];
        float w4 = dtW[c * 8 + 4], w5 = dtW[c * 8 + 5], w6 = dtW[c * 8 + 6], w7 = dtW[c * 8 + 7];
        float bbv = dtb[c];
        for (int r = 0; r < 64; ++r) {
            int t = t0 + r;
            if (t >= LSEQ) break;
            float a = bbv;
            a = fmaf(sdbl[r][0], w0, a); a = fmaf(sdbl[r][1], w1, a);
            a = fmaf(sdbl[r][2], w2, a); a = fmaf(sdbl[r][3], w3, a);
            a = fmaf(sdbl[r][4], w4, a); a = fmaf(sdbl[r][5], w5, a);
            a = fmaf(sdbl[r][6], w6, a); a = fmaf(sdbl[r][7], w7, a);
            float sp = (a > 20.f) ? a : log1pf(__expf(a));
            dtt[(rb + t) * 256 + c] = sp;
        }
    }
}

// ---------------- selective scan: LDS-staged (single phase), 3-pass ---------
__global__ __launch_bounds__(256) void scan1_kernel(
    const float* __restrict__ dt, const float* __restrict__ u,
    const float* __restrict__ dbl, const float* __restrict__ Alog,
    float* __restrict__ P, float* __restrict__ S)
{
    __shared__ float sdt[40][64], su[40][64], sB[40][16];
    int bid = blockIdx.x;
    int dg = bid & 3;
    int rest = bid >> 2;
    int ch = rest % CHN;
    int b  = rest / CHN;
    int tid = threadIdx.x;
    int ng = tid & 3, di = tid >> 2;
    int d0 = dg * 64, d = d0 + di, n0 = ng * 4;
    int r0 = b * LSEQ + ch * LCH;
#pragma unroll
    for (int l = 0; l < 3; ++l) {
        int j = tid + l * 256;
        if (j < 640) {
            int row = j >> 4, q = (j & 15) << 2;
            size_t s = (size_t)(r0 + row) * 256 + d0 + q;
            *(float4*)&sdt[row][q] = *(const float4*)&dt[s];
            *(float4*)&su [row][q] = *(const float4*)&u [s];
        }
    }
    if (tid < 160) {
        int row = tid >> 2, q = (tid & 3) << 2;
        *(float4*)&sB[row][q] = *(const float4*)&dbl[(size_t)(r0 + row) * 40 + 8 + q];
    }
    float A2[4];
#pragma unroll
    for (int j = 0; j < 4; ++j) A2[j] = -__expf(Alog[d * 16 + n0 + j]);
    float p[4] = {1.f, 1.f, 1.f, 1.f}, s[4] = {0.f, 0.f, 0.f, 0.f};
    __syncthreads();
#pragma unroll 4
    for (int qi = 0; qi < LCH; ++qi) {
        float dtv = sdt[qi][di];
        float dtu = dtv * su[qi][di];
        float4 Br = *(const float4*)&sB[qi][n0];
        float bv[4] = {Br.x, Br.y, Br.z, Br.w};
#pragma unroll
        for (int j = 0; j < 4; ++j) {
            float a = __expf(dtv * A2[j]);
            p[j] *= a;
            s[j] = fmaf(a, s[j], dtu * bv[j]);
        }
    }
    size_t ob = ((size_t)(b * CHN + ch) * 256 + d) * 16 + n0;
    *(float4*)&P[ob] = make_float4(p[0], p[1], p[2], p[3]);
    *(float4*)&S[ob] = make_float4(s[0], s[1], s[2], s[3]);
}

__global__ __launch_bounds__(256) void scan2_kernel(
    const float* __restrict__ P, const float* __restrict__ S, float* __restrict__ H0)
{
    int idx = blockIdx.x * 256 + threadIdx.x;
    int n = idx & 15;
    int d = (idx >> 4) & 255;
    int b = idx >> 12;
    float h = 0.f;
    for (int ch = 0; ch < CHN; ++ch) {
        size_t o = ((size_t)(b * CHN + ch) * 256 + d) * 16 + n;
        H0[o] = h;
        h = fmaf(P[o], h, S[o]);
    }
}

__global__ __launch_bounds__(256) void scan3_kernel(
    const float* __restrict__ dt, const float* __restrict__ u,
    const float* __restrict__ dbl, const float* __restrict__ Alog,
    const float* __restrict__ H0, const float* __restrict__ Dp,
    const float* __restrict__ xz, unsigned short* __restrict__ gh,
    unsigned short* __restrict__ gl)
{
    __shared__ float sdt[40][64], su[40][64], sz[40][64], sB[40][16], sC[40][16];
    int bid = blockIdx.x;
    int dg = bid & 3;
    int rest = bid >> 2;
    int ch = rest % CHN;
    int b  = rest / CHN;
    int tid = threadIdx.x;
    int ng = tid & 3, di = tid >> 2;
    int d0 = dg * 64, d = d0 + di, n0 = ng * 4;
    int r0 = b * LSEQ + ch * LCH;
#pragma unroll
    for (int l = 0; l < 3; ++l) {
        int j = tid + l * 256;
        if (j < 640) {
            int row = j >> 4, q = (j & 15) << 2;
            size_t s = (size_t)(r0 + row) * 256 + d0 + q;
            *(float4*)&sdt[row][q] = *(const float4*)&dt[s];
            *(float4*)&su [row][q] = *(const float4*)&u [s];
            *(float4*)&sz [row][q] = *(const float4*)&xz[(size_t)(r0 + row) * 512 + 256 + d0 + q];
        }
    }
    if (tid < 160) {
        int row = tid >> 2, q = (tid & 3) << 2;
        *(float4*)&sB[row][q] = *(const float4*)&dbl[(size_t)(r0 + row) * 40 + 8 + q];
        *(float4*)&sC[row][q] = *(const float4*)&dbl[(size_t)(r0 + row) * 40 + 24 + q];
    }
    float A2[4];
#pragma unroll
    for (int j = 0; j < 4; ++j) A2[j] = -__expf(Alog[d * 16 + n0 + j]);
    size_t ob = ((size_t)(b * CHN + ch) * 256 + d) * 16 + n0;
    float4 h4 = *(const float4*)&H0[ob];
    float h[4] = {h4.x, h4.y, h4.z, h4.w};
    float Dpd = Dp[d];
    __syncthreads();
    for (int qi = 0; qi < LCH; ++qi) {
        float dtv = sdt[qi][di];
        float uv  = su[qi][di];
        float dtu = dtv * uv;
        float4 Br = *(const float4*)&sB[qi][n0];
        float4 Cr = *(const float4*)&sC[qi][n0];
        float bv[4] = {Br.x, Br.y, Br.z, Br.w};
        float cv[4] = {Cr.x, Cr.y, Cr.z, Cr.w};
        float pacc = 0.f;
#pragma unroll
        for (int j = 0; j < 4; ++j) {
            float a = __expf(dtv * A2[j]);
            h[j] = fmaf(a, h[j], dtu * bv[j]);
            pacc = fmaf(h[j], cv[j], pacc);
        }
        float acc = pacc + __shfl_xor(pacc, 1);
        acc += __shfl_xor(acc, 2);
        float yv = fmaf(uv, Dpd, acc);
        float gv = yv * silu_f(sz[qi][di]);
        if (ng == 0) sz[qi][di] = gv;
    }
    __syncthreads();
#pragma unroll
    for (int l = 0; l < 3; ++l) {
        int j = tid + l * 256;
        if (j < 640) {
            int row = j >> 4, q = (j & 15) << 2;
            float4 gv4 = *(const float4*)&sz[row][q];
            float gv[4] = {gv4.x, gv4.y, gv4.z, gv4.w};
            alignas(8) unsigned short hs[4], ls[4];
#pragma unroll
            for (int jj = 0; jj < 4; ++jj) split_bf(gv[jj], hs[jj], ls[jj]);
            size_t o = (size_t)(r0 + row) * 256 + d0 + q;
            *(short4v*)&gh[o] = *(short4v*)hs;
            *(short4v*)&gl[o] = *(short4v*)ls;
        }
    }
}

// ---------------- mean pool + final fc ----------------
__global__ __launch_bounds__(128) void pool1_kernel(
    const float* __restrict__ fused, float* __restrict__ part)
{
    int d = threadIdx.x;
    int blk = blockIdx.x;
    int ch = blk % CHN;
    int b  = blk / CHN;
    int t0 = ch * LCH;
    float s = 0.f;
    for (int q = 0; q < LCH; ++q)
        s += fused[((size_t)(b * LSEQ + t0 + q)) * 128 + d];
    part[(size_t)(b * CHN + ch) * 128 + d] = s;
}

__global__ __launch_bounds__(128) void pool2_kernel(
    const float* __restrict__ part, const float* __restrict__ fcW,
    const float* __restrict__ fcb, float* __restrict__ out)
{
    __shared__ float pl[128];
    int d = threadIdx.x;
    int b = blockIdx.x;
    float s = 0.f;
    for (int ch = 0; ch < CHN; ++ch) s += part[(size_t)(b * CHN + ch) * 128 + d];
    pl[d] = s * (1.f / 1080.f);
    __syncthreads();
    if (d < 3) {
        float a = fcb[d];
        for (int dd = 0; dd < 128; ++dd) a = fmaf(pl[dd], fcW[d * 128 + dd], a);
        out[b * 3 + d] = a;
    }
}

// ---------------- host orchestration ----------------
extern "C" void kernel_launch(void* const* d_in, const int* in_sizes, int n_in,
                              void* d_out, int out_size, void* d_ws, size_t ws_size,
                              hipStream_t stream)
{
    const float* x    = (const float*)d_in[0];
    const float* embW = (const float*)d_in[1];
    const float* embb = (const float*)d_in[2];
    const float* c3W  = (const float*)d_in[3];
    const float* c3b  = (const float*)d_in[4];
    const float* bn3  = (const float*)d_in[5];
    const float* c5W  = (const float*)d_in[6];
    const float* c5b  = (const float*)d_in[7];
    const float* bn5  = (const float*)d_in[8];
    const float* c7W  = (const float*)d_in[9];
    const float* c7b  = (const float*)d_in[10];
    const float* bn7  = (const float*)d_in[11];
    const float* cfW  = (const float*)d_in[12];
    const float* cfb  = (const float*)d_in[13];
    const float* bnf  = (const float*)d_in[14];
    const float* lng  = (const float*)d_in[15];
    const float* lnb  = (const float*)d_in[16];
    const float* inW  = (const float*)d_in[17];
    const float* mcW  = (const float*)d_in[18];
    const float* mcb  = (const float*)d_in[19];
    const float* xpW  = (const float*)d_in[20];
    const float* dtW  = (const float*)d_in[21];
    const float* dtbp = (const float*)d_in[22];
    const float* Alog = (const float*)d_in[23];
    const float* Dp   = (const float*)d_in[24];
    const float* outW = (const float*)d_in[25];
    const float* flW  = (const float*)d_in[26];
    const float* flb  = (const float*)d_in[27];
    const float* fcW  = (const float*)d_in[28];
    const float* fcb  = (const float*)d_in[29];

    float* ws = (float*)d_ws;
    size_t off = 0;
    auto alloc = [&](size_t n) { float* p = ws + off; off += n; return p; };
    float* xe   = alloc((size_t)BLROWS * 128);
    float* xz   = alloc((size_t)BLROWS * 512);   // head doubles as 'fused'
    float* ub   = alloc((size_t)BLROWS * 256);
    float* dtt  = alloc((size_t)BLROWS * 256);
    float* dbl  = alloc((size_t)BLROWS * 40);
    float* Pb   = alloc((size_t)NBATCH * CHN * 256 * 16);  // reused as pool partials
    float* Sb   = alloc((size_t)NBATCH * CHN * 256 * 16);
    float* h0b  = alloc((size_t)NBATCH * CHN * 256 * 16);
    float* schpack = alloc(640);
    float* fused = xz;

    off = (off + 3) & ~(size_t)3;
    unsigned short* us = (unsigned short*)(ws + off);
    size_t uo = 0;
    auto ualloc = [&](size_t n) { unsigned short* p = us + uo; uo += n; return p; };
    unsigned short* cch  = ualloc((size_t)BLROWS * 192);  // also lnxh
    unsigned short* ccl  = ualloc((size_t)BLROWS * 192);  // also lnxl
    unsigned short* finh = ualloc((size_t)BLROWS * 256);
    unsigned short* finl = ualloc((size_t)BLROWS * 256);
    unsigned short* gbh  = ualloc((size_t)BLROWS * 256);
    unsigned short* gbl  = ualloc((size_t)BLROWS * 256);
    unsigned short* xeh  = ualloc((size_t)BLROWS * 128);
    unsigned short* xel  = ualloc((size_t)BLROWS * 128);
    unsigned short* w192h = ualloc((size_t)192 * 896); unsigned short* w192l = ualloc((size_t)192 * 896);
    unsigned short* cfh = ualloc(128 * 192); unsigned short* cfl = ualloc(128 * 192);
    unsigned short* inh = ualloc((size_t)1536 * 128); unsigned short* inl = ualloc((size_t)1536 * 128);
    unsigned short* xph = ualloc((size_t)3 * 64 * 256); unsigned short* xpl = ualloc((size_t)3 * 64 * 256);
    unsigned short* oth = ualloc((size_t)384 * 256); unsigned short* otl = ualloc((size_t)384 * 256);
    unsigned short* flh = ualloc((size_t)128 * 256); unsigned short* fll = ualloc((size_t)128 * 256);
    unsigned short* lnxh = cch;
    unsigned short* lnxl = ccl;
    (void)ws_size; (void)in_sizes; (void)n_in; (void)out_size;

    // 0. weights + scale/shift packing
    convw_all<<<(JOB_END + 255) / 256, 256, 0, stream>>>(
        c3W, c5W, c7W, cfW, inW, xpW, outW, flW,
        c3b, c5b, c7b, bn3, bn5, bn7, cfb, bnf,
        w192h, w192l, cfh, cfl, inh, inl, xph, xpl, oth, otl, flh, fll, schpack);

    // 1. embedding + positional encoding (fp32 + hi/lo)
    embed_kernel<<<(BLROWS * 128) / 256, 256, 0, stream>>>(x, embW, embb, xe, xeh, xel);

    // 2. CNN branch
    dim3 gconv(3, 17, NBATCH);
    gemm_conv<<<gconv, 256, 0, stream>>>(xeh, xel, w192h, w192l, schpack, schpack + 192, cch, ccl);
    dim3 g17(1, 17, NBATCH);
    gemm_plain<64, 128><<<g17, 256, 0, stream>>>(
        cch, ccl, 192, cfh, cfl, 192, 128, 1,
        schpack + 384, schpack + 512, nullptr, nullptr, 0, finh, finl, 256);

    // 3. input LN for block 0 (later blocks get LN fused into out-proj)
    ln_kernel<<<BLROWS / 4, 256, 0, stream>>>(xe, lng, lnb, lnxh, lnxl);

    // 4. three mamba blocks
    const int SCAN_BLKS = NBATCH * CHN * 4;   // 1728
    for (int i = 0; i < 3; ++i) {
        dim3 gin(4, 17, NBATCH);
        gemm_plain<64, 128><<<gin, 256, 0, stream>>>(
            lnxh, lnxl, 128, inh + (size_t)i * 512 * 128, inl + (size_t)i * 512 * 128, 128,
            512, 0, nullptr, nullptr, nullptr, xz, 512, nullptr, nullptr, 0);

        // fused mconv + x-proj + dt-softplus
        dim3 gmxd(17, NBATCH);
        mxd_kernel<<<gmxd, 256, 0, stream>>>(
            xz, mcW + i * 256 * 4, mcb + i * 256,
            xph + (size_t)i * 64 * 256, xpl + (size_t)i * 64 * 256,
            dtW + i * 256 * 8, dtbp + i * 256,
            ub, dbl, dtt);

        scan1_kernel<<<SCAN_BLKS, 256, 0, stream>>>(
            dtt, ub, dbl, Alog + i * 256 * 16, Pb, Sb);
        scan2_kernel<<<(NBATCH * 256 * 16) / 256, 256, 0, stream>>>(Pb, Sb, h0b);
        scan3_kernel<<<SCAN_BLKS, 256, 0, stream>>>(
            dtt, ub, dbl, Alog + i * 256 * 16, h0b, Dp + i * 256, xz, gbh, gbl);

        if (i < 2) {
            // out-proj with fused layernorm (params of the NEXT block) -> lnx
            gemm_plain<64, 128><<<g17, 256, 0, stream>>>(
                gbh, gbl, 256, oth + (size_t)i * 128 * 256, otl + (size_t)i * 128 * 256, 256,
                128, 4, lng + (i + 1) * 128, lnb + (i + 1) * 128, nullptr,
                nullptr, 0, lnxh, lnxl, 128);
        } else {
            gemm_plain<64, 128><<<g17, 256, 0, stream>>>(
                gbh, gbl, 256, oth + (size_t)i * 128 * 256, otl + (size_t)i * 128 * 256, 256,
                128, 3, nullptr, nullptr, nullptr, nullptr, 0, finh + 128, finl + 128, 256);
        }
    }

    // 5. fusion linear + relu
    gemm_plain<64, 128><<<g17, 256, 0, stream>>>(
        finh, finl, 256, flh, fll, 256, 128, 2,
        nullptr, nullptr, flb, fused, 128, nullptr, nullptr, 0);

    // 6. mean pool + final fc
    pool1_kernel<<<NBATCH * CHN, 128, 0, stream>>>(fused, Pb);
    pool2_kernel<<<NBATCH, 128, 0, stream>>>(Pb, fcW, fcb, (float*)d_out);
}

// Round 15
// 645.732 us; speedup vs baseline: 1.2872x; 1.2872x over previous
//
#include <hip/hip_runtime.h>
#include <math.h>

#define LSEQ   1080
#define NBATCH 16
#define BLROWS (LSEQ*NBATCH)   // 17280
#define CHN    27
#define LCH    40              // 27*40 = 1080

#define LPAD 44
#define LPADB 140

typedef __bf16  bf16x8 __attribute__((ext_vector_type(8)));
typedef float   f32x4  __attribute__((ext_vector_type(4)));
typedef short   short8 __attribute__((ext_vector_type(8)));
typedef short   short4v __attribute__((ext_vector_type(4)));

__device__ __forceinline__ float silu_f(float x) { return x / (1.f + __expf(-x)); }

__device__ __forceinline__ unsigned short f2bf(float f) {
    unsigned int u = __float_as_uint(f);
    u += 0x7fffu + ((u >> 16) & 1u);
    return (unsigned short)(u >> 16);
}
__device__ __forceinline__ float bf2f(unsigned short h) {
    return __uint_as_float(((unsigned int)h) << 16);
}
__device__ __forceinline__ void split_bf(float v, unsigned short& h, unsigned short& l) {
    h = f2bf(v);
    l = f2bf(v - bf2f(h));
}

// ---------------- embed + positional encoding (fp32 + pre-split hi/lo) ------
__global__ __launch_bounds__(256) void embed_kernel(
    const float* __restrict__ x, const float* __restrict__ embW,
    const float* __restrict__ embb, float* __restrict__ xe,
    unsigned short* __restrict__ xeh, unsigned short* __restrict__ xel)
{
    int idx = blockIdx.x * 256 + threadIdx.x;
    if (idx >= BLROWS * 128) return;
    int d = idx & 127;
    int r = idx >> 7;
    int t = r % LSEQ;
    float x0 = x[(size_t)r * 2], x1 = x[(size_t)r * 2 + 1];
    int i2 = d & 126;
    float div = expf((float)i2 * (-9.210340371976184f / 128.f));
    float arg = (float)t * div;
    float pe = (d & 1) ? cosf(arg) : sinf(arg);
    float v = fmaf(x0, embW[d], fmaf(x1, embW[128 + d], embb[d] + pe));
    xe[idx] = v;
    unsigned short h, l;
    split_bf(v, h, l);
    xeh[idx] = h; xel[idx] = l;
}

// ---------------- all weight conversions + scale/shift packing --------------
#define JOB_W192  172032
#define JOB_CF    196608
#define JOB_IN    393216
#define JOB_XP    442368
#define JOB_OT    540672
#define JOB_FL    573440
#define JOB_END   574080
__global__ __launch_bounds__(256) void convw_all(
    const float* __restrict__ c3W, const float* __restrict__ c5W,
    const float* __restrict__ c7W, const float* __restrict__ cfW,
    const float* __restrict__ inW, const float* __restrict__ xpW,
    const float* __restrict__ otW, const float* __restrict__ flW,
    const float* __restrict__ c3b, const float* __restrict__ c5b, const float* __restrict__ c7b,
    const float* __restrict__ bn3, const float* __restrict__ bn5, const float* __restrict__ bn7,
    const float* __restrict__ cfb, const float* __restrict__ bnf,
    unsigned short* __restrict__ w192h, unsigned short* __restrict__ w192l,
    unsigned short* __restrict__ cfh, unsigned short* __restrict__ cfl,
    unsigned short* __restrict__ inh, unsigned short* __restrict__ inl,
    unsigned short* __restrict__ xph, unsigned short* __restrict__ xpl,
    unsigned short* __restrict__ oth, unsigned short* __restrict__ otl,
    unsigned short* __restrict__ flh, unsigned short* __restrict__ fll,
    float* __restrict__ schpack)
{
    int idx = blockIdx.x * 256 + threadIdx.x;
    if (idx >= JOB_END) return;
    float v;
    unsigned short *dh, *dl;
    int off;
    if (idx < JOB_W192) {
        off = idx;
        int n = off / 896, kk = off % 896;
        int slot = kk >> 7, d = kk & 127;
        int br = n >> 6, c = n & 63;
        int KT = 3 + 2 * br, pad = 1 + br;
        int tp = slot - 3 + pad;
        const float* w = (br == 0) ? c3W : (br == 1) ? c5W : c7W;
        v = (tp >= 0 && tp < KT) ? w[((c << 7) + d) * KT + tp] : 0.f;
        dh = w192h; dl = w192l;
    } else if (idx < JOB_CF) {
        off = idx - JOB_W192; v = cfW[off]; dh = cfh; dl = cfl;
    } else if (idx < JOB_IN) {
        off = idx - JOB_CF; v = inW[off]; dh = inh; dl = inl;
    } else if (idx < JOB_XP) {
        off = idx - JOB_IN;
        int k = off & 255, n = (off >> 8) & 63, blk = off >> 14;
        v = (n < 40) ? xpW[((size_t)blk * 40 + n) * 256 + k] : 0.f;
        dh = xph; dl = xpl;
    } else if (idx < JOB_OT) {
        off = idx - JOB_XP; v = otW[off]; dh = oth; dl = otl;
    } else if (idx < JOB_FL) {
        off = idx - JOB_OT; v = flW[off]; dh = flh; dl = fll;
    } else {
        int j = idx - JOB_FL;
        if (j < 384) {
            int col = (j < 192) ? j : j - 192;
            int isSh = j >= 192;
            int br = col >> 6, c = col & 63;
            const float* bn = (br == 0) ? bn3 : (br == 1) ? bn5 : bn7;
            float bias = ((br == 0) ? c3b : (br == 1) ? c5b : c7b)[c];
            float g = bn[c], bb = bn[64 + c], m = bn[128 + c], vv = bn[192 + c];
            float scale = g * rsqrtf(vv + 1e-5f);
            float shift = (bias - m) * scale + bb;
            schpack[j] = isSh ? shift : scale;
        } else {
            int j2 = j - 384;
            int col = j2 & 127;
            int isSh = j2 >= 128;
            float g = bnf[col], bb = bnf[128 + col], m = bnf[256 + col], vv = bnf[384 + col];
            float scale = g * rsqrtf(vv + 1e-5f);
            float shift = (cfb[col] - m) * scale + bb;
            schpack[384 + j2] = isSh ? shift : scale;
        }
        return;
    }
    unsigned short h, l;
    split_bf(v, h, l);
    dh[off] = h; dl[off] = l;
}

// ---------------- CNN front-end: halo GEMM over unified 7-tap weights -------
__global__ __launch_bounds__(256) void gemm_conv(
    const unsigned short* __restrict__ Xh, const unsigned short* __restrict__ Xl,
    const unsigned short* __restrict__ Wh, const unsigned short* __restrict__ Wl,
    const float* __restrict__ sc, const float* __restrict__ sh,
    unsigned short* __restrict__ Ch, unsigned short* __restrict__ Cl)
{
    __shared__ unsigned short Ah[70][LPAD], Al[70][LPAD];
    __shared__ unsigned short Bh[64][LPADB], Bl[64][LPADB];
    const int tid = threadIdx.x;
    const int n0 = blockIdx.x * 64, t0 = blockIdx.y * 64, b = blockIdx.z;
    const size_t boff = (size_t)b * LSEQ;
    const int lane = tid & 63, wid = tid >> 6;
    const int wr = wid >> 1, wc = wid & 1;
    const int fr = lane & 15, fq = lane >> 4;
    const short8 zz = {0, 0, 0, 0, 0, 0, 0, 0};
    f32x4 acc[2][2];
#pragma unroll
    for (int m = 0; m < 2; ++m)
#pragma unroll
        for (int n = 0; n < 2; ++n) acc[m][n] = (f32x4){0.f, 0.f, 0.f, 0.f};

    for (int ks = 0; ks < 128; ks += 32) {
#pragma unroll
        for (int l = 0; l < 2; ++l) {
            int c = tid + l * 256;
            if (c < 280) {
                int row = c >> 2, kc = (c & 3) << 3;
                int ts = t0 - 3 + row;
                short8 vh = zz, vl = zz;
                if (ts >= 0 && ts < LSEQ) {
                    size_t s = (boff + ts) * 128 + ks + kc;
                    vh = *(const short8*)&Xh[s];
                    vl = *(const short8*)&Xl[s];
                }
                *(short8*)&Ah[row][kc] = vh;
                *(short8*)&Al[row][kc] = vl;
            }
        }
        for (int g = 0; g < 2; ++g) {
            const int ntap = (g == 0) ? 4 : 3;
#pragma unroll
            for (int l = 0; l < 4; ++l) {
                int c = tid + l * 256;
                int col = c >> 4, rem = c & 15, tt = rem >> 2, kq = (rem & 3) << 3;
                if (tt < ntap) {
                    int tap = g * 4 + tt;
                    size_t s = (size_t)(n0 + col) * 896 + tap * 128 + ks + kq;
                    *(short8*)&Bh[col][tt * 32 + kq] = *(const short8*)&Wh[s];
                    *(short8*)&Bl[col][tt * 32 + kq] = *(const short8*)&Wl[s];
                }
            }
            __syncthreads();
            for (int tt = 0; tt < ntap; ++tt) {
                int tap = g * 4 + tt;
                bf16x8 bhf[2], blf[2];
#pragma unroll
                for (int n = 0; n < 2; ++n) {
                    int col = wc * 32 + n * 16 + fr;
                    bhf[n] = __builtin_bit_cast(bf16x8, *(const short8*)&Bh[col][tt * 32 + fq * 8]);
                    blf[n] = __builtin_bit_cast(bf16x8, *(const short8*)&Bl[col][tt * 32 + fq * 8]);
                }
#pragma unroll
                for (int m = 0; m < 2; ++m) {
                    int rowA = wr * 32 + m * 16 + fr + tap;
                    bf16x8 ahf = __builtin_bit_cast(bf16x8, *(const short8*)&Ah[rowA][fq * 8]);
                    bf16x8 alf = __builtin_bit_cast(bf16x8, *(const short8*)&Al[rowA][fq * 8]);
#pragma unroll
                    for (int n = 0; n < 2; ++n) {
                        acc[m][n] = __builtin_amdgcn_mfma_f32_16x16x32_bf16(ahf, bhf[n], acc[m][n], 0, 0, 0);
                        acc[m][n] = __builtin_amdgcn_mfma_f32_16x16x32_bf16(ahf, blf[n], acc[m][n], 0, 0, 0);
                        acc[m][n] = __builtin_amdgcn_mfma_f32_16x16x32_bf16(alf, bhf[n], acc[m][n], 0, 0, 0);
                    }
                }
            }
            __syncthreads();
        }
    }
    unsigned short* Chb = Ch + (size_t)b * LSEQ * 192;
    unsigned short* Clb = Cl + (size_t)b * LSEQ * 192;
#pragma unroll
    for (int m = 0; m < 2; ++m) {
#pragma unroll
        for (int n = 0; n < 2; ++n) {
            int colg = n0 + wc * 32 + n * 16 + fr;
            float scl = sc[colg], shf2 = sh[colg];
#pragma unroll
            for (int r = 0; r < 4; ++r) {
                int t = t0 + wr * 32 + m * 16 + fq * 4 + r;
                if (t >= LSEQ) continue;
                float v = fmaf(acc[m][n][r], scl, shf2);
                v = v > 0.f ? v : 0.f;
                unsigned short h, l;
                split_bf(v, h, l);
                Chb[(size_t)t * 192 + colg] = h;
                Clb[(size_t)t * 192 + colg] = l;
            }
        }
    }
}

// ---------------- generic MFMA GEMM, pre-split A and W ----------------------
// epi: 0 fp32 | 1 relu(sc,sh)->hi/lo | 2 relu+bias fp32 | 3 hi/lo
//      4 layernorm(sc=gamma,sh=beta)->hi/lo (BM=64,BN=128,grid.x=1 only)
template<int BM, int BN>
__global__ __launch_bounds__(256) void gemm_plain(
    const unsigned short* __restrict__ Aph, const unsigned short* __restrict__ Apl, int lda,
    const unsigned short* __restrict__ Wh, const unsigned short* __restrict__ Wl, int Kd,
    int Ntot, int epi,
    const float* __restrict__ sc, const float* __restrict__ sh, const float* __restrict__ bias,
    float* __restrict__ Cf, int ldc,
    unsigned short* __restrict__ Ch, unsigned short* __restrict__ Cl, int ldch)
{
    constexpr int WM = BM / 2, WN = BN / 2;
    constexpr int MR = WM / 16, NR = WN / 16;
    constexpr int ACH = (BM * 4) / 256;
    constexpr int BCH = (BN * 4) / 256;
    __shared__ unsigned short Ah[BM][LPAD], Al[BM][LPAD];
    __shared__ unsigned short Bh[BN][LPAD], Bl[BN][LPAD];
    const int tid = threadIdx.x;
    const int b = blockIdx.z, t0 = blockIdx.y * BM, n0 = blockIdx.x * BN;
    const unsigned short* Abh = Aph + (size_t)b * LSEQ * lda;
    const unsigned short* Abl = Apl + (size_t)b * LSEQ * lda;
    const int lane = tid & 63, wid = tid >> 6;
    const int wr = wid >> 1, wc = wid & 1;
    const int fr = lane & 15, fq = lane >> 4;
    f32x4 acc[MR][NR];
#pragma unroll
    for (int m = 0; m < MR; ++m)
#pragma unroll
        for (int n = 0; n < NR; ++n) acc[m][n] = (f32x4){0.f, 0.f, 0.f, 0.f};

    const short8 zz = {0, 0, 0, 0, 0, 0, 0, 0};
    for (int ks = 0; ks < Kd; ks += 32) {
#pragma unroll
        for (int l = 0; l < ACH; ++l) {
            int c = tid + l * 256;
            int row = c >> 2, kc = (c & 3) << 3;
            int t = t0 + row;
            short8 vh = zz, vl = zz;
            if (t < LSEQ) {
                size_t s = (size_t)t * lda + ks + kc;
                vh = *(const short8*)&Abh[s];
                vl = *(const short8*)&Abl[s];
            }
            *(short8*)&Ah[row][kc] = vh;
            *(short8*)&Al[row][kc] = vl;
        }
#pragma unroll
        for (int l = 0; l < BCH; ++l) {
            int c = tid + l * 256;
            int col = c >> 2, kc = (c & 3) << 3;
            size_t s = (size_t)(n0 + col) * Kd + ks + kc;
            *(short8*)&Bh[col][kc] = *(const short8*)&Wh[s];
            *(short8*)&Bl[col][kc] = *(const short8*)&Wl[s];
        }
        __syncthreads();
        bf16x8 bhf[NR], blf[NR];
#pragma unroll
        for (int n = 0; n < NR; ++n) {
            int col = wc * WN + n * 16 + fr;
            bhf[n] = __builtin_bit_cast(bf16x8, *(const short8*)&Bh[col][fq * 8]);
            blf[n] = __builtin_bit_cast(bf16x8, *(const short8*)&Bl[col][fq * 8]);
        }
#pragma unroll
        for (int m = 0; m < MR; ++m) {
            int rowr = wr * WM + m * 16 + fr;
            bf16x8 ahf = __builtin_bit_cast(bf16x8, *(const short8*)&Ah[rowr][fq * 8]);
            bf16x8 alf = __builtin_bit_cast(bf16x8, *(const short8*)&Al[rowr][fq * 8]);
#pragma unroll
            for (int n = 0; n < NR; ++n) {
                acc[m][n] = __builtin_amdgcn_mfma_f32_16x16x32_bf16(ahf, bhf[n], acc[m][n], 0, 0, 0);
                acc[m][n] = __builtin_amdgcn_mfma_f32_16x16x32_bf16(ahf, blf[n], acc[m][n], 0, 0, 0);
                acc[m][n] = __builtin_amdgcn_mfma_f32_16x16x32_bf16(alf, bhf[n], acc[m][n], 0, 0, 0);
            }
        }
        __syncthreads();
    }

    float* Cfb = Cf ? Cf + (size_t)b * LSEQ * ldc : nullptr;
    unsigned short* Chb = Ch ? Ch + (size_t)b * LSEQ * ldch : nullptr;
    unsigned short* Clb = Cl ? Cl + (size_t)b * LSEQ * ldch : nullptr;

    if (epi == 4) {
        float* red = reinterpret_cast<float*>(&Ah[0][0]);   // [64][2]
        float part[MR][4], mu[MR][4], rs[MR][4];
#pragma unroll
        for (int m = 0; m < MR; ++m)
#pragma unroll
            for (int r = 0; r < 4; ++r) {
                float p = 0.f;
#pragma unroll
                for (int n = 0; n < NR; ++n) p += acc[m][n][r];
#pragma unroll
                for (int o2 = 1; o2 < 16; o2 <<= 1) p += __shfl_xor(p, o2, 64);
                part[m][r] = p;
            }
        if (fr == 0) {
#pragma unroll
            for (int m = 0; m < MR; ++m)
#pragma unroll
                for (int r = 0; r < 4; ++r)
                    red[(wr * 32 + m * 16 + fq * 4 + r) * 2 + wc] = part[m][r];
        }
        __syncthreads();
#pragma unroll
        for (int m = 0; m < MR; ++m)
#pragma unroll
            for (int r = 0; r < 4; ++r) {
                int row = wr * 32 + m * 16 + fq * 4 + r;
                mu[m][r] = (red[row * 2] + red[row * 2 + 1]) * (1.f / 128.f);
            }
        __syncthreads();
#pragma unroll
        for (int m = 0; m < MR; ++m)
#pragma unroll
            for (int r = 0; r < 4; ++r) {
                float p = 0.f;
#pragma unroll
                for (int n = 0; n < NR; ++n) {
                    float dv = acc[m][n][r] - mu[m][r];
                    p = fmaf(dv, dv, p);
                }
#pragma unroll
                for (int o2 = 1; o2 < 16; o2 <<= 1) p += __shfl_xor(p, o2, 64);
                part[m][r] = p;
            }
        if (fr == 0) {
#pragma unroll
            for (int m = 0; m < MR; ++m)
#pragma unroll
                for (int r = 0; r < 4; ++r)
                    red[(wr * 32 + m * 16 + fq * 4 + r) * 2 + wc] = part[m][r];
        }
        __syncthreads();
#pragma unroll
        for (int m = 0; m < MR; ++m)
#pragma unroll
            for (int r = 0; r < 4; ++r) {
                int row = wr * 32 + m * 16 + fq * 4 + r;
                rs[m][r] = rsqrtf((red[row * 2] + red[row * 2 + 1]) * (1.f / 128.f) + 1e-5f);
            }
#pragma unroll
        for (int m = 0; m < MR; ++m) {
#pragma unroll
            for (int n = 0; n < NR; ++n) {
                int colg = wc * WN + n * 16 + fr;
                float g = sc[colg], b2 = sh[colg];
#pragma unroll
                for (int r = 0; r < 4; ++r) {
                    int t = t0 + wr * WM + m * 16 + fq * 4 + r;
                    if (t >= LSEQ) continue;
                    float v = (acc[m][n][r] - mu[m][r]) * rs[m][r] * g + b2;
                    unsigned short h, l;
                    split_bf(v, h, l);
                    Chb[(size_t)t * ldch + colg] = h;
                    Clb[(size_t)t * ldch + colg] = l;
                }
            }
        }
        return;
    }

#pragma unroll
    for (int m = 0; m < MR; ++m) {
#pragma unroll
        for (int n = 0; n < NR; ++n) {
            int colg = n0 + wc * WN + n * 16 + fr;
            if (colg >= Ntot) continue;
#pragma unroll
            for (int r = 0; r < 4; ++r) {
                int t = t0 + wr * WM + m * 16 + fq * 4 + r;
                if (t >= LSEQ) continue;
                float v = acc[m][n][r];
                if (epi == 0) {
                    Cfb[(size_t)t * ldc + colg] = v;
                } else if (epi == 1) {
                    v = fmaf(v, sc[colg], sh[colg]);
                    v = v > 0.f ? v : 0.f;
                    unsigned short h, l;
                    split_bf(v, h, l);
                    Chb[(size_t)t * ldch + colg] = h;
                    Clb[(size_t)t * ldch + colg] = l;
                } else if (epi == 2) {
                    v += bias[colg];
                    v = v > 0.f ? v : 0.f;
                    Cfb[(size_t)t * ldc + colg] = v;
                } else {
                    unsigned short h, l;
                    split_bf(v, h, l);
                    Chb[(size_t)t * ldch + colg] = h;
                    Clb[(size_t)t * ldch + colg] = l;
                }
            }
        }
    }
}

// ---------------- layernorm (standalone, block 0 input only) ----------------
__global__ __launch_bounds__(256) void ln_kernel(
    const float* __restrict__ in, const float* __restrict__ g,
    const float* __restrict__ b2, unsigned short* __restrict__ oh,
    unsigned short* __restrict__ ol)
{
    int lane = threadIdx.x & 63;
    int wid  = threadIdx.x >> 6;
    int row = blockIdx.x * 4 + wid;
    if (row >= BLROWS) return;
    const float* rp = in + (size_t)row * 128;
    float v0 = rp[lane], v1 = rp[lane + 64];
    float s = v0 + v1;
#pragma unroll
    for (int o2 = 32; o2 > 0; o2 >>= 1) s += __shfl_xor(s, o2, 64);
    float mu = s * (1.f / 128.f);
    float d0 = v0 - mu, d1 = v1 - mu;
    float q = d0 * d0 + d1 * d1;
#pragma unroll
    for (int o2 = 32; o2 > 0; o2 >>= 1) q += __shfl_xor(q, o2, 64);
    float rs = 1.f / sqrtf(q * (1.f / 128.f) + 1e-5f);
    float y0 = d0 * rs * g[lane]      + b2[lane];
    float y1 = d1 * rs * g[lane + 64] + b2[lane + 64];
    unsigned short h, l;
    size_t o = (size_t)row * 128;
    split_bf(y0, h, l); oh[o + lane] = h;      ol[o + lane] = l;
    split_bf(y1, h, l); oh[o + lane + 64] = h; ol[o + lane + 64] = l;
}

// ---------------- depthwise causal conv (K=4) + silu -> fp32 + hi/lo --------
__global__ __launch_bounds__(256) void mconv_kernel(
    const float* __restrict__ xz, const float* __restrict__ Wc,
    const float* __restrict__ bc, float* __restrict__ u,
    unsigned short* __restrict__ uh, unsigned short* __restrict__ ul)
{
    int idx = blockIdx.x * 256 + threadIdx.x;
    int c = idx & 255;
    int r = idx >> 8;
    if (r >= BLROWS) return;
    int t = r % LSEQ;
    const float* xs = xz + (size_t)r * 512 + c;
    float acc = bc[c];
    if (t >= 3) acc = fmaf(xs[-3 * 512], Wc[c * 4 + 0], acc);
    if (t >= 2) acc = fmaf(xs[-2 * 512], Wc[c * 4 + 1], acc);
    if (t >= 1) acc = fmaf(xs[-1 * 512], Wc[c * 4 + 2], acc);
    acc = fmaf(xs[0], Wc[c * 4 + 3], acc);
    float uv = silu_f(acc);
    size_t o = (size_t)r * 256 + c;
    u[o] = uv;
    unsigned short h, l;
    split_bf(uv, h, l);
    uh[o] = h; ul[o] = l;
}

// ---------------- dt = softplus(dbl[:, :8] @ dt_W.T + dt_b) ----------------
__global__ __launch_bounds__(256) void dtk_kernel(
    const float* __restrict__ dbl, const float* __restrict__ dtW,
    const float* __restrict__ dtb, float* __restrict__ dtout)
{
    int idx = blockIdx.x * 256 + threadIdx.x;
    int c = idx & 255;
    int r = idx >> 8;
    if (r >= BLROWS) return;
    const float* dr = dbl + (size_t)r * 40;
    float a = dtb[c];
#pragma unroll
    for (int j = 0; j < 8; ++j) a = fmaf(dr[j], dtW[c * 8 + j], a);
    float sp = (a > 20.f) ? a : log1pf(__expf(a));
    dtout[(size_t)r * 256 + c] = sp;
}

// ---------------- selective scan: LDS-staged (single phase), 3-pass ---------
__global__ __launch_bounds__(256) void scan1_kernel(
    const float* __restrict__ dt, const float* __restrict__ u,
    const float* __restrict__ dbl, const float* __restrict__ Alog,
    float* __restrict__ P, float* __restrict__ S)
{
    __shared__ float sdt[40][64], su[40][64], sB[40][16];
    int bid = blockIdx.x;
    int dg = bid & 3;
    int rest = bid >> 2;
    int ch = rest % CHN;
    int b  = rest / CHN;
    int tid = threadIdx.x;
    int ng = tid & 3, di = tid >> 2;
    int d0 = dg * 64, d = d0 + di, n0 = ng * 4;
    int r0 = b * LSEQ + ch * LCH;
#pragma unroll
    for (int l = 0; l < 3; ++l) {
        int j = tid + l * 256;
        if (j < 640) {
            int row = j >> 4, q = (j & 15) << 2;
            size_t s = (size_t)(r0 + row) * 256 + d0 + q;
            *(float4*)&sdt[row][q] = *(const float4*)&dt[s];
            *(float4*)&su [row][q] = *(const float4*)&u [s];
        }
    }
    if (tid < 160) {
        int row = tid >> 2, q = (tid & 3) << 2;
        *(float4*)&sB[row][q] = *(const float4*)&dbl[(size_t)(r0 + row) * 40 + 8 + q];
    }
    float A2[4];
#pragma unroll
    for (int j = 0; j < 4; ++j) A2[j] = -__expf(Alog[d * 16 + n0 + j]);
    float p[4] = {1.f, 1.f, 1.f, 1.f}, s[4] = {0.f, 0.f, 0.f, 0.f};
    __syncthreads();
#pragma unroll 4
    for (int qi = 0; qi < LCH; ++qi) {
        float dtv = sdt[qi][di];
        float dtu = dtv * su[qi][di];
        float4 Br = *(const float4*)&sB[qi][n0];
        float bv[4] = {Br.x, Br.y, Br.z, Br.w};
#pragma unroll
        for (int j = 0; j < 4; ++j) {
            float a = __expf(dtv * A2[j]);
            p[j] *= a;
            s[j] = fmaf(a, s[j], dtu * bv[j]);
        }
    }
    size_t ob = ((size_t)(b * CHN + ch) * 256 + d) * 16 + n0;
    *(float4*)&P[ob] = make_float4(p[0], p[1], p[2], p[3]);
    *(float4*)&S[ob] = make_float4(s[0], s[1], s[2], s[3]);
}

__global__ __launch_bounds__(256) void scan2_kernel(
    const float* __restrict__ P, const float* __restrict__ S, float* __restrict__ H0)
{
    int idx = blockIdx.x * 256 + threadIdx.x;
    int n = idx & 15;
    int d = (idx >> 4) & 255;
    int b = idx >> 12;
    float h = 0.f;
    for (int ch = 0; ch < CHN; ++ch) {
        size_t o = ((size_t)(b * CHN + ch) * 256 + d) * 16 + n;
        H0[o] = h;
        h = fmaf(P[o], h, S[o]);
    }
}

__global__ __launch_bounds__(256) void scan3_kernel(
    const float* __restrict__ dt, const float* __restrict__ u,
    const float* __restrict__ dbl, const float* __restrict__ Alog,
    const float* __restrict__ H0, const float* __restrict__ Dp,
    const float* __restrict__ xz, unsigned short* __restrict__ gh,
    unsigned short* __restrict__ gl)
{
    __shared__ float sdt[40][64], su[40][64], sz[40][64], sB[40][16], sC[40][16];
    int bid = blockIdx.x;
    int dg = bid & 3;
    int rest = bid >> 2;
    int ch = rest % CHN;
    int b  = rest / CHN;
    int tid = threadIdx.x;
    int ng = tid & 3, di = tid >> 2;
    int d0 = dg * 64, d = d0 + di, n0 = ng * 4;
    int r0 = b * LSEQ + ch * LCH;
#pragma unroll
    for (int l = 0; l < 3; ++l) {
        int j = tid + l * 256;
        if (j < 640) {
            int row = j >> 4, q = (j & 15) << 2;
            size_t s = (size_t)(r0 + row) * 256 + d0 + q;
            *(float4*)&sdt[row][q] = *(const float4*)&dt[s];
            *(float4*)&su [row][q] = *(const float4*)&u [s];
            *(float4*)&sz [row][q] = *(const float4*)&xz[(size_t)(r0 + row) * 512 + 256 + d0 + q];
        }
    }
    if (tid < 160) {
        int row = tid >> 2, q = (tid & 3) << 2;
        *(float4*)&sB[row][q] = *(const float4*)&dbl[(size_t)(r0 + row) * 40 + 8 + q];
        *(float4*)&sC[row][q] = *(const float4*)&dbl[(size_t)(r0 + row) * 40 + 24 + q];
    }
    float A2[4];
#pragma unroll
    for (int j = 0; j < 4; ++j) A2[j] = -__expf(Alog[d * 16 + n0 + j]);
    size_t ob = ((size_t)(b * CHN + ch) * 256 + d) * 16 + n0;
    float4 h4 = *(const float4*)&H0[ob];
    float h[4] = {h4.x, h4.y, h4.z, h4.w};
    float Dpd = Dp[d];
    __syncthreads();
    for (int qi = 0; qi < LCH; ++qi) {
        float dtv = sdt[qi][di];
        float uv  = su[qi][di];
        float dtu = dtv * uv;
        float4 Br = *(const float4*)&sB[qi][n0];
        float4 Cr = *(const float4*)&sC[qi][n0];
        float bv[4] = {Br.x, Br.y, Br.z, Br.w};
        float cv[4] = {Cr.x, Cr.y, Cr.z, Cr.w};
        float pacc = 0.f;
#pragma unroll
        for (int j = 0; j < 4; ++j) {
            float a = __expf(dtv * A2[j]);
            h[j] = fmaf(a, h[j], dtu * bv[j]);
            pacc = fmaf(h[j], cv[j], pacc);
        }
        float acc = pacc + __shfl_xor(pacc, 1);
        acc += __shfl_xor(acc, 2);
        float yv = fmaf(uv, Dpd, acc);
        float gv = yv * silu_f(sz[qi][di]);
        if (ng == 0) sz[qi][di] = gv;
    }
    __syncthreads();
#pragma unroll
    for (int l = 0; l < 3; ++l) {
        int j = tid + l * 256;
        if (j < 640) {
            int row = j >> 4, q = (j & 15) << 2;
            float4 gv4 = *(const float4*)&sz[row][q];
            float gv[4] = {gv4.x, gv4.y, gv4.z, gv4.w};
            alignas(8) unsigned short hs[4], ls[4];
#pragma unroll
            for (int jj = 0; jj < 4; ++jj) split_bf(gv[jj], hs[jj], ls[jj]);
            size_t o = (size_t)(r0 + row) * 256 + d0 + q;
            *(short4v*)&gh[o] = *(short4v*)hs;
            *(short4v*)&gl[o] = *(short4v*)ls;
        }
    }
}

// ---------------- mean pool + final fc ----------------
__global__ __launch_bounds__(128) void pool1_kernel(
    const float* __restrict__ fused, float* __restrict__ part)
{
    int d = threadIdx.x;
    int blk = blockIdx.x;
    int ch = blk % CHN;
    int b  = blk / CHN;
    int t0 = ch * LCH;
    float s = 0.f;
    for (int q = 0; q < LCH; ++q)
        s += fused[((size_t)(b * LSEQ + t0 + q)) * 128 + d];
    part[(size_t)(b * CHN + ch) * 128 + d] = s;
}

__global__ __launch_bounds__(128) void pool2_kernel(
    const float* __restrict__ part, const float* __restrict__ fcW,
    const float* __restrict__ fcb, float* __restrict__ out)
{
    __shared__ float pl[128];
    int d = threadIdx.x;
    int b = blockIdx.x;
    float s = 0.f;
    for (int ch = 0; ch < CHN; ++ch) s += part[(size_t)(b * CHN + ch) * 128 + d];
    pl[d] = s * (1.f / 1080.f);
    __syncthreads();
    if (d < 3) {
        float a = fcb[d];
        for (int dd = 0; dd < 128; ++dd) a = fmaf(pl[dd], fcW[d * 128 + dd], a);
        out[b * 3 + d] = a;
    }
}

// ---------------- host orchestration ----------------
extern "C" void kernel_launch(void* const* d_in, const int* in_sizes, int n_in,
                              void* d_out, int out_size, void* d_ws, size_t ws_size,
                              hipStream_t stream)
{
    const float* x    = (const float*)d_in[0];
    const float* embW = (const float*)d_in[1];
    const float* embb = (const float*)d_in[2];
    const float* c3W  = (const float*)d_in[3];
    const float* c3b  = (const float*)d_in[4];
    const float* bn3  = (const float*)d_in[5];
    const float* c5W  = (const float*)d_in[6];
    const float* c5b  = (const float*)d_in[7];
    const float* bn5  = (const float*)d_in[8];
    const float* c7W  = (const float*)d_in[9];
    const float* c7b  = (const float*)d_in[10];
    const float* bn7  = (const float*)d_in[11];
    const float* cfW  = (const float*)d_in[12];
    const float* cfb  = (const float*)d_in[13];
    const float* bnf  = (const float*)d_in[14];
    const float* lng  = (const float*)d_in[15];
    const float* lnb  = (const float*)d_in[16];
    const float* inW  = (const float*)d_in[17];
    const float* mcW  = (const float*)d_in[18];
    const float* mcb  = (const float*)d_in[19];
    const float* xpW  = (const float*)d_in[20];
    const float* dtW  = (const float*)d_in[21];
    const float* dtbp = (const float*)d_in[22];
    const float* Alog = (const float*)d_in[23];
    const float* Dp   = (const float*)d_in[24];
    const float* outW = (const float*)d_in[25];
    const float* flW  = (const float*)d_in[26];
    const float* flb  = (const float*)d_in[27];
    const float* fcW  = (const float*)d_in[28];
    const float* fcb  = (const float*)d_in[29];

    float* ws = (float*)d_ws;
    size_t off = 0;
    auto alloc = [&](size_t n) { float* p = ws + off; off += n; return p; };
    float* xe   = alloc((size_t)BLROWS * 128);
    float* xz   = alloc((size_t)BLROWS * 512);   // head doubles as 'fused'
    float* ub   = alloc((size_t)BLROWS * 256);
    float* dtt  = alloc((size_t)BLROWS * 256);
    float* dbl  = alloc((size_t)BLROWS * 40);
    float* Pb   = alloc((size_t)NBATCH * CHN * 256 * 16);  // reused as pool partials
    float* Sb   = alloc((size_t)NBATCH * CHN * 256 * 16);
    float* h0b  = alloc((size_t)NBATCH * CHN * 256 * 16);
    float* schpack = alloc(640);
    float* fused = xz;

    off = (off + 3) & ~(size_t)3;
    unsigned short* us = (unsigned short*)(ws + off);
    size_t uo = 0;
    auto ualloc = [&](size_t n) { unsigned short* p = us + uo; uo += n; return p; };
    unsigned short* cch  = ualloc((size_t)BLROWS * 192);  // also lnxh
    unsigned short* ccl  = ualloc((size_t)BLROWS * 192);  // also lnxl
    unsigned short* finh = ualloc((size_t)BLROWS * 256);
    unsigned short* finl = ualloc((size_t)BLROWS * 256);
    unsigned short* ubh  = ualloc((size_t)BLROWS * 256);  // also gbh
    unsigned short* ubl  = ualloc((size_t)BLROWS * 256);  // also gbl
    unsigned short* xeh  = ualloc((size_t)BLROWS * 128);
    unsigned short* xel  = ualloc((size_t)BLROWS * 128);
    unsigned short* w192h = ualloc((size_t)192 * 896); unsigned short* w192l = ualloc((size_t)192 * 896);
    unsigned short* cfh = ualloc(128 * 192); unsigned short* cfl = ualloc(128 * 192);
    unsigned short* inh = ualloc((size_t)1536 * 128); unsigned short* inl = ualloc((size_t)1536 * 128);
    unsigned short* xph = ualloc((size_t)3 * 64 * 256); unsigned short* xpl = ualloc((size_t)3 * 64 * 256);
    unsigned short* oth = ualloc((size_t)384 * 256); unsigned short* otl = ualloc((size_t)384 * 256);
    unsigned short* flh = ualloc((size_t)128 * 256); unsigned short* fll = ualloc((size_t)128 * 256);
    unsigned short* lnxh = cch;
    unsigned short* lnxl = ccl;
    unsigned short* gbh  = ubh;
    unsigned short* gbl  = ubl;
    (void)ws_size; (void)in_sizes; (void)n_in; (void)out_size;

    // 0. weights + scale/shift packing
    convw_all<<<(JOB_END + 255) / 256, 256, 0, stream>>>(
        c3W, c5W, c7W, cfW, inW, xpW, outW, flW,
        c3b, c5b, c7b, bn3, bn5, bn7, cfb, bnf,
        w192h, w192l, cfh, cfl, inh, inl, xph, xpl, oth, otl, flh, fll, schpack);

    // 1. embedding + positional encoding (fp32 + hi/lo)
    embed_kernel<<<(BLROWS * 128) / 256, 256, 0, stream>>>(x, embW, embb, xe, xeh, xel);

    // 2. CNN branch
    dim3 gconv(3, 17, NBATCH);
    gemm_conv<<<gconv, 256, 0, stream>>>(xeh, xel, w192h, w192l, schpack, schpack + 192, cch, ccl);
    dim3 g17(1, 17, NBATCH);
    gemm_plain<64, 128><<<g17, 256, 0, stream>>>(
        cch, ccl, 192, cfh, cfl, 192, 128, 1,
        schpack + 384, schpack + 512, nullptr, nullptr, 0, finh, finl, 256);

    // 3. input LN for block 0 (later blocks get LN fused into out-proj)
    ln_kernel<<<BLROWS / 4, 256, 0, stream>>>(xe, lng, lnb, lnxh, lnxl);

    // 4. three mamba blocks
    const int SCAN_BLKS = NBATCH * CHN * 4;   // 1728
    for (int i = 0; i < 3; ++i) {
        dim3 gin(4, 17, NBATCH);
        gemm_plain<64, 128><<<gin, 256, 0, stream>>>(
            lnxh, lnxl, 128, inh + (size_t)i * 512 * 128, inl + (size_t)i * 512 * 128, 128,
            512, 0, nullptr, nullptr, nullptr, xz, 512, nullptr, nullptr, 0);

        mconv_kernel<<<BLROWS, 256, 0, stream>>>(xz, mcW + i * 256 * 4, mcb + i * 256, ub, ubh, ubl);

        gemm_plain<64, 64><<<g17, 256, 0, stream>>>(
            ubh, ubl, 256, xph + (size_t)i * 64 * 256, xpl + (size_t)i * 64 * 256, 256,
            40, 0, nullptr, nullptr, nullptr, dbl, 40, nullptr, nullptr, 0);

        dtk_kernel<<<BLROWS, 256, 0, stream>>>(dbl, dtW + i * 256 * 8, dtbp + i * 256, dtt);

        scan1_kernel<<<SCAN_BLKS, 256, 0, stream>>>(
            dtt, ub, dbl, Alog + i * 256 * 16, Pb, Sb);
        scan2_kernel<<<(NBATCH * 256 * 16) / 256, 256, 0, stream>>>(Pb, Sb, h0b);
        scan3_kernel<<<SCAN_BLKS, 256, 0, stream>>>(
            dtt, ub, dbl, Alog + i * 256 * 16, h0b, Dp + i * 256, xz, gbh, gbl);

        if (i < 2) {
            // out-proj with fused layernorm (params of the NEXT block) -> lnx
            gemm_plain<64, 128><<<g17, 256, 0, stream>>>(
                gbh, gbl, 256, oth + (size_t)i * 128 * 256, otl + (size_t)i * 128 * 256, 256,
                128, 4, lng + (i + 1) * 128, lnb + (i + 1) * 128, nullptr,
                nullptr, 0, lnxh, lnxl, 128);
        } else {
            gemm_plain<64, 128><<<g17, 256, 0, stream>>>(
                gbh, gbl, 256, oth + (size_t)i * 128 * 256, otl + (size_t)i * 128 * 256, 256,
                128, 3, nullptr, nullptr, nullptr, nullptr, 0, finh + 128, finl + 128, 256);
        }
    }

    // 5. fusion linear + relu
    gemm_plain<64, 128><<<g17, 256, 0, stream>>>(
        finh, finl, 256, flh, fll, 256, 128, 2,
        nullptr, nullptr, flb, fused, 128, nullptr, nullptr, 0);

    // 6. mean pool + final fc
    pool1_kernel<<<NBATCH * CHN, 128, 0, stream>>>(fused, Pb);
    pool2_kernel<<<NBATCH, 128, 0, stream>>>(Pb, fcW, fcb, (float*)d_out);
}